// Round 4
// baseline (161.770 us; speedup 1.0000x reference)
//
#include <hip/hip_runtime.h>

typedef float  f32x4  __attribute__((ext_vector_type(4)));
typedef __bf16 bf16x8 __attribute__((ext_vector_type(8)));
typedef unsigned short u16x8 __attribute__((ext_vector_type(8)));

#define NL2E (-1.44269504088896f)   // -log2(e)
#define TL2E ( 2.88539008177793f)   // 2*log2(e)

// z pre-scaled: sigmoid -> z = -log2e*(x+b), tanh -> z = 2log2e*(x+b)
__device__ __forceinline__ float sigm_z(float z) {
    return __builtin_amdgcn_rcpf(1.0f + __builtin_amdgcn_exp2f(z));
}
__device__ __forceinline__ float tanh_z(float z) {
    return 1.0f - 2.0f * __builtin_amdgcn_rcpf(1.0f + __builtin_amdgcn_exp2f(z));
}

// 8 batches/WG, 512 WGs -> 2 WG/CU (2 waves/SIMD) so the partner WG's issue
// fills this WG's barrier/ds/dep stalls. Round-3 minimal structure otherwise:
// wave w owns gate-tiles at hidden block w (all 4 gates), single barrier/step,
// gates consumed in-register. A rows 0..15 = batch (row&7) (dup M-fill).
// Elementwise: lane (q,hi) handles 2 cells, batches {4(hi&1)+2(hi>>1), +1},
// reg-pair selected by cndmask on hi<2 (no dynamic reg indexing).
__global__ __launch_bounds__(256, 2) void lstm_fused(
    const float* __restrict__ x,      // [4096][256][16]
    const float* __restrict__ w_ih1,  // [256][16]
    const float* __restrict__ w_hh1,  // [256][64]
    const float* __restrict__ b_ih1, const float* __restrict__ b_hh1,
    const float* __restrict__ w_ih2,  // [4][64]
    const float* __restrict__ w_hh2,  // [4]
    const float* __restrict__ b_ih2, const float* __restrict__ b_hh2,
    const float* __restrict__ fc_w, const float* __restrict__ fc_b,
    float* __restrict__ out)          // [4096][256]
{
    __shared__ unsigned short A_h[2 * 8 * 64];      // 2KB dbuf h1 bf16 [buf][b][he]
    __shared__ unsigned short Xc[2 * 8 * 16 * 32];  // 16KB dbuf x bf16 [buf][b][tt][k] (k>=16 zero)
    __shared__ float Pre2[2][32];                   // dbuf layer-2 preacts [buf][b*4+g]
    __shared__ float Ybuf[8][16];                   // [b][tt]

    const int tid = threadIdx.x;
    const int wv  = tid >> 6;
    const int l   = tid & 63;
    const int q   = l & 15;
    const int hi  = l >> 4;
    const int b0  = blockIdx.x << 3;
    const int he  = (wv << 4) + q;

    // stagger the second WG on each CU (~448cy) to seed anti-phase overlap
    if ((blockIdx.x >> 8) & 1) __builtin_amdgcn_s_sleep(7);

    // zero h state (both bufs)
    if (tid < 128) ((u16x8*)A_h)[tid] = (u16x8){0,0,0,0,0,0,0,0};
    // zero x pad columns (k=16..31) in both bufs, once
    {
        const int sb = tid >> 5, sr = tid & 31, st = sr >> 1, sh = sr & 1;
        const u16x8 z = {0,0,0,0,0,0,0,0};
        #pragma unroll
        for (int buf = 0; buf < 2; ++buf) {
            *(u16x8*)((char*)Xc + buf * 8192 + sb * 1024
                      + ((st * 64 + 32 + sh * 16) ^ (sb << 4))) = z;
        }
    }

    // ---- B fragments, pre-scaled so MFMA acc is directly the exp2 argument ----
    bf16x8 Bf[4][3];
    #pragma unroll
    for (int g = 0; g < 4; ++g) {
        const float sc = (g == 2) ? TL2E : NL2E;
        const int n = (g << 6) + (wv << 4) + q;
        #pragma unroll
        for (int ks = 0; ks < 3; ++ks) {
            bf16x8 tmp;
            #pragma unroll
            for (int j = 0; j < 8; ++j) {
                const int k = ks * 32 + hi * 8 + j;
                float v = 0.f;
                if (k < 64)      v = w_hh1[n * 64 + k];
                else if (k < 80) v = w_ih1[n * 16 + (k - 64)];
                tmp[j] = (__bf16)(sc * v);
            }
            Bf[g][ks] = tmp;
        }
    }
    bf16x8 B2[2];                                   // layer-2 input proj (wave 3)
    {
        const float sc2 = (q == 2) ? TL2E : NL2E;
        #pragma unroll
        for (int ks = 0; ks < 2; ++ks) {
            bf16x8 tmp;
            #pragma unroll
            for (int j = 0; j < 8; ++j) {
                const int k = ks * 32 + hi * 8 + j;
                const float v = (q < 4) ? w_ih2[q * 64 + k] : 0.f;
                tmp[j] = (__bf16)(sc2 * v);
            }
            B2[ks] = tmp;
        }
    }

    // layer-1 biases as scaled acc-init (per lane: hidden he, bcast over rows)
    float accb[4];
    #pragma unroll
    for (int g = 0; g < 4; ++g) {
        const float sc = (g == 2) ? TL2E : NL2E;
        accb[g] = sc * (b_ih1[(g << 6) + he] + b_hh1[(g << 6) + he]);
    }

    // layer-2 constants (scaled)
    const float w2si = NL2E * w_hh2[0], w2sf = NL2E * w_hh2[1];
    const float w2sg = TL2E * w_hh2[2], w2so = NL2E * w_hh2[3];
    const float nb2i = NL2E * (b_ih2[0] + b_hh2[0]);
    const float nb2f = NL2E * (b_ih2[1] + b_hh2[1]);
    const float tb2g = TL2E * (b_ih2[2] + b_hh2[2]);
    const float nb2o = NL2E * (b_ih2[3] + b_hh2[3]);
    const float fcw = fc_w[0], fcb = fc_b[0];

    // ---- x staging: thread (sb,st,sh) owns x[b0+sb][t0+st][sh*8 .. +7] ----
    const int sb = tid >> 5, sr = tid & 31, st = sr >> 1, sh = sr & 1;
    const unsigned xoff = (unsigned)(sb * 1024 + ((st * 64 + sh * 16) ^ (sb << 4)));
    const float* xrow = x + (size_t)(b0 + sb) * 4096 + st * 16 + sh * 8;

    f32x4 xqa, xqb;
    auto ldx = [&](int t) {
        const float* p = xrow + t * 16;
        xqa = ((const f32x4*)p)[0]; xqb = ((const f32x4*)p)[1];
    };
    auto stage_x = [&](int bufoff) {
        bf16x8 v;
        #pragma unroll
        for (int j = 0; j < 4; ++j) { v[j] = (__bf16)xqa[j]; v[4 + j] = (__bf16)xqb[j]; }
        *(u16x8*)((char*)Xc + bufoff + xoff) = __builtin_bit_cast(u16x8, v);
    };
    ldx(0); stage_x(0); ldx(16);

    // invariant addresses
    const int rb = q & 7;                            // A row -> batch
    const unsigned ar0 = (unsigned)(rb * 128 + ((hi * 16)      ^ (rb << 4)));
    const unsigned ar1 = (unsigned)(rb * 128 + ((64 + hi * 16) ^ (rb << 4)));
    const unsigned xro = (unsigned)(rb * 1024);      // + ((tt*64 + hi*16) ^ (rb<<4))
    const unsigned xrs = (unsigned)(hi * 16);
    const int bA = ((hi & 1) << 2) + ((hi >> 1) << 1);
    const int bB = bA + 1;
    const unsigned awA = (unsigned)(bA * 128 + ((he * 2) ^ (bA << 4)));
    const unsigned awB = (unsigned)(bB * 128 + ((he * 2) ^ (bB << 4)));

    float cA = 0.f, cB = 0.f;      // layer-1 cell state (2 cells/lane)
    float h2 = 0.f, c2 = 0.f;      // layer-2 state (wave 1, lanes 0..7)

    __syncthreads();

    #pragma unroll 2
    for (int t = 0; t < 256; ++t) {
        const int tt = t & 15;
        if (tt == 0 && t + 16 < 256) {
            stage_x((((t >> 4) + 1) & 1) << 13);     // next chunk -> idle buf
            if (t + 32 < 256) ldx(t + 32);
        }

        // A-frag reads: h_{t-1} from buf (t-1)&1, x from current chunk buf
        const int rbo = ((t + 1) & 1) << 10;
        const u16x8 ra0 = *(const u16x8*)((const char*)A_h + rbo + ar0);
        const u16x8 ra1 = *(const u16x8*)((const char*)A_h + rbo + ar1);
        const u16x8 ra2 = *(const u16x8*)((const char*)Xc + (((t >> 4) & 1) << 13)
                                          + xro + (((tt << 6) + xrs) ^ (rb << 4)));

        // layer-2 + FC at lag 2 (wave 1, lanes 0..7 = batches)
        if (wv == 1 && l < 8 && t >= 2) {
            const f32x4 p2 = *(const f32x4*)&Pre2[(t + 1) & 1][l << 2];
            const float zi = p2[0] + __builtin_fmaf(w2si, h2, nb2i);
            const float zf = p2[1] + __builtin_fmaf(w2sf, h2, nb2f);
            const float zg = p2[2] + __builtin_fmaf(w2sg, h2, tb2g);
            const float zo = p2[3] + __builtin_fmaf(w2so, h2, nb2o);
            const float i2 = sigm_z(zi), f2v = sigm_z(zf);
            const float g2v = tanh_z(zg), o2 = sigm_z(zo);
            c2 = __builtin_fmaf(f2v, c2, i2 * g2v);
            h2 = o2 * tanh_z(c2 * TL2E);
            const int s = t - 2;
            Ybuf[l][s & 15] = __builtin_fmaf(fcw, h2, fcb);
            if ((s & 15) == 15) {
                float* op = out + (size_t)(b0 + l) * 256 + (s - 15);
                const f32x4* yb = (const f32x4*)Ybuf[l];
                ((f32x4*)op)[0] = yb[0]; ((f32x4*)op)[1] = yb[1];
                ((f32x4*)op)[2] = yb[2]; ((f32x4*)op)[3] = yb[3];
            }
        }

        const bf16x8 a0 = __builtin_bit_cast(bf16x8, ra0);
        const bf16x8 a1 = __builtin_bit_cast(bf16x8, ra1);
        const bf16x8 a2 = __builtin_bit_cast(bf16x8, ra2);

        f32x4 g0 = {accb[0], accb[0], accb[0], accb[0]};
        f32x4 g1 = {accb[1], accb[1], accb[1], accb[1]};
        f32x4 g2 = {accb[2], accb[2], accb[2], accb[2]};
        f32x4 g3 = {accb[3], accb[3], accb[3], accb[3]};
        g0 = __builtin_amdgcn_mfma_f32_16x16x32_bf16(a0, Bf[0][0], g0, 0, 0, 0);
        g1 = __builtin_amdgcn_mfma_f32_16x16x32_bf16(a0, Bf[1][0], g1, 0, 0, 0);
        g2 = __builtin_amdgcn_mfma_f32_16x16x32_bf16(a0, Bf[2][0], g2, 0, 0, 0);
        g3 = __builtin_amdgcn_mfma_f32_16x16x32_bf16(a0, Bf[3][0], g3, 0, 0, 0);
        g0 = __builtin_amdgcn_mfma_f32_16x16x32_bf16(a1, Bf[0][1], g0, 0, 0, 0);
        g1 = __builtin_amdgcn_mfma_f32_16x16x32_bf16(a1, Bf[1][1], g1, 0, 0, 0);
        g2 = __builtin_amdgcn_mfma_f32_16x16x32_bf16(a1, Bf[2][1], g2, 0, 0, 0);
        g3 = __builtin_amdgcn_mfma_f32_16x16x32_bf16(a1, Bf[3][1], g3, 0, 0, 0);
        g0 = __builtin_amdgcn_mfma_f32_16x16x32_bf16(a2, Bf[0][2], g0, 0, 0, 0);
        g1 = __builtin_amdgcn_mfma_f32_16x16x32_bf16(a2, Bf[1][2], g1, 0, 0, 0);
        g2 = __builtin_amdgcn_mfma_f32_16x16x32_bf16(a2, Bf[2][2], g2, 0, 0, 0);
        g3 = __builtin_amdgcn_mfma_f32_16x16x32_bf16(a2, Bf[3][2], g3, 0, 0, 0);

        if (wv == 3) {   // layer-2 input projection of h_{t-1} -> Pre2[t&1]
            f32x4 p4 = {0.f, 0.f, 0.f, 0.f};
            p4 = __builtin_amdgcn_mfma_f32_16x16x32_bf16(a0, B2[0], p4, 0, 0, 0);
            p4 = __builtin_amdgcn_mfma_f32_16x16x32_bf16(a1, B2[1], p4, 0, 0, 0);
            if (hi < 2 && q < 4) {
                #pragma unroll
                for (int r = 0; r < 4; ++r) Pre2[t & 1][(((hi << 2) + r) << 2) + q] = p4[r];
            }
        }

        // ---- elementwise: 2 cells/lane; reg-pair select via cndmask on hi<2 ----
        const bool lo = (hi < 2);
        const float zIA = lo ? g0[0] : g0[2], zIB = lo ? g0[1] : g0[3];
        const float zFA = lo ? g1[0] : g1[2], zFB = lo ? g1[1] : g1[3];
        const float zGA = lo ? g2[0] : g2[2], zGB = lo ? g2[1] : g2[3];
        const float zOA = lo ? g3[0] : g3[2], zOB = lo ? g3[1] : g3[3];

        char* AW = (char*)A_h + ((t & 1) << 10);
        {
            const float iv = sigm_z(zIA), fv = sigm_z(zFA);
            const float gv = tanh_z(zGA), ov = sigm_z(zOA);
            cA = __builtin_fmaf(fv, cA, iv * gv);
            const float hv = ov * tanh_z(cA * TL2E);
            *(unsigned short*)(AW + awA) = __builtin_bit_cast(unsigned short, (__bf16)hv);
        }
        {
            const float iv = sigm_z(zIB), fv = sigm_z(zFB);
            const float gv = tanh_z(zGB), ov = sigm_z(zOB);
            cB = __builtin_fmaf(fv, cB, iv * gv);
            const float hv = ov * tanh_z(cB * TL2E);
            *(unsigned short*)(AW + awB) = __builtin_bit_cast(unsigned short, (__bf16)hv);
        }
        __syncthreads();
    }

    // ---- epilogue: layer-2 steps s=254 (Pre2[1]) and s=255 (fresh proj h_255) ----
    if (wv == 3) {
        const u16x8 ra0 = *(const u16x8*)((const char*)A_h + 1024 + ar0);
        const u16x8 ra1 = *(const u16x8*)((const char*)A_h + 1024 + ar1);
        f32x4 p4 = {0.f, 0.f, 0.f, 0.f};
        p4 = __builtin_amdgcn_mfma_f32_16x16x32_bf16(__builtin_bit_cast(bf16x8, ra0), B2[0], p4, 0, 0, 0);
        p4 = __builtin_amdgcn_mfma_f32_16x16x32_bf16(__builtin_bit_cast(bf16x8, ra1), B2[1], p4, 0, 0, 0);
        if (hi < 2 && q < 4) {
            #pragma unroll
            for (int r = 0; r < 4; ++r) Pre2[0][(((hi << 2) + r) << 2) + q] = p4[r];
        }
    }
    __syncthreads();
    if (wv == 1 && l < 8) {
        #pragma unroll
        for (int e = 0; e < 2; ++e) {              // e=0 -> s=254 (Pre2[1]), e=1 -> s=255 (Pre2[0])
            const f32x4 p2 = *(const f32x4*)&Pre2[1 - e][l << 2];
            const float zi = p2[0] + __builtin_fmaf(w2si, h2, nb2i);
            const float zf = p2[1] + __builtin_fmaf(w2sf, h2, nb2f);
            const float zg = p2[2] + __builtin_fmaf(w2sg, h2, tb2g);
            const float zo = p2[3] + __builtin_fmaf(w2so, h2, nb2o);
            const float i2 = sigm_z(zi), f2v = sigm_z(zf);
            const float g2v = tanh_z(zg), o2 = sigm_z(zo);
            c2 = __builtin_fmaf(f2v, c2, i2 * g2v);
            h2 = o2 * tanh_z(c2 * TL2E);
            Ybuf[l][14 + e] = __builtin_fmaf(fcw, h2, fcb);
        }
        float* op = out + (size_t)(b0 + l) * 256 + 240;
        const f32x4* yb = (const f32x4*)Ybuf[l];
        ((f32x4*)op)[0] = yb[0]; ((f32x4*)op)[1] = yb[1];
        ((f32x4*)op)[2] = yb[2]; ((f32x4*)op)[3] = yb[3];
    }
}

extern "C" void kernel_launch(void* const* d_in, const int* in_sizes, int n_in,
                              void* d_out, int out_size, void* d_ws, size_t ws_size,
                              hipStream_t stream) {
    (void)in_sizes; (void)n_in; (void)out_size; (void)d_ws; (void)ws_size;
    const float* x     = (const float*)d_in[0];
    const float* w_ih1 = (const float*)d_in[1];
    const float* w_hh1 = (const float*)d_in[2];
    const float* b_ih1 = (const float*)d_in[3];
    const float* b_hh1 = (const float*)d_in[4];
    const float* w_ih2 = (const float*)d_in[5];
    const float* w_hh2 = (const float*)d_in[6];
    const float* b_ih2 = (const float*)d_in[7];
    const float* b_hh2 = (const float*)d_in[8];
    const float* fc_w  = (const float*)d_in[9];
    const float* fc_b  = (const float*)d_in[10];
    lstm_fused<<<dim3(512), dim3(256), 0, stream>>>(
        x, w_ih1, w_hh1, b_ih1, b_hh1, w_ih2, w_hh2, b_ih2, b_hh2, fc_w, fc_b,
        (float*)d_out);
}

// Round 6
// 160.286 us; speedup vs baseline: 1.0093x; 1.0093x over previous
//
#include <hip/hip_runtime.h>

typedef float  f32x4  __attribute__((ext_vector_type(4)));
typedef __bf16 bf16x8 __attribute__((ext_vector_type(8)));
typedef unsigned short u16x8 __attribute__((ext_vector_type(8)));

#define NL2E (-1.44269504088896f)   // -log2(e)
#define TL2E ( 2.88539008177793f)   // 2*log2(e)

// LSTM cell from pre-scaled gate args (zi,zf,zo = -log2e*pre, zg = 2log2e*pre).
// 3-rcp form: i*g=(Eg-1)/((1+Ei)(1+Eg)), f=1/(1+Ef), o*tanh(c)=(Ec-1)/((1+Eo)(1+Ec)).
__device__ __forceinline__ float cell_update(float zi, float zf, float zg, float zo, float& c) {
    const float Ei = __builtin_amdgcn_exp2f(zi);
    const float Ef = __builtin_amdgcn_exp2f(zf);
    const float Eg = __builtin_amdgcn_exp2f(zg);
    const float Eo = __builtin_amdgcn_exp2f(zo);
    const float ig = (Eg - 1.0f) * __builtin_amdgcn_rcpf((1.0f + Ei) * (1.0f + Eg));
    const float fv = __builtin_amdgcn_rcpf(1.0f + Ef);
    c = __builtin_fmaf(fv, c, ig);
    const float zc = fminf(fmaxf(TL2E * c, -60.0f), 60.0f);   // guard exp2 overflow
    const float Ec = __builtin_amdgcn_exp2f(zc);
    return (Ec - 1.0f) * __builtin_amdgcn_rcpf((1.0f + Eo) * (1.0f + Ec));   // o*tanh(c)
}

// 16 batches/WG, 4 waves, grid 256 (1 WG/CU). One RAW barrier per timestep
// (lgkmcnt-only: global loads/stores stay in flight across steps).
// Wave w owns N-tiles {w,w+4,w+8,w+12} -> lane (q,hi) holds all 4 gates of
// hidden he=16w+q for batches 4hi+j in its MFMA accs (no Pre LDS round-trip).
__global__ __launch_bounds__(256, 1) void lstm_fused(
    const float* __restrict__ x,      // [4096][256][16]
    const float* __restrict__ w_ih1,  // [256][16]
    const float* __restrict__ w_hh1,  // [256][64]
    const float* __restrict__ b_ih1, const float* __restrict__ b_hh1,
    const float* __restrict__ w_ih2,  // [4][64]
    const float* __restrict__ w_hh2,  // [4]
    const float* __restrict__ b_ih2, const float* __restrict__ b_hh2,
    const float* __restrict__ fc_w, const float* __restrict__ fc_b,
    float* __restrict__ out)          // [4096][256]
{
    __shared__ unsigned short A_h[2 * 16 * 64];        // 4KB dbuf h1 bf16 [buf][b][he], ^((b&7)<<4)
    __shared__ unsigned short Xc[2 * 16 * 16 * 32];    // 32KB dbuf x bf16 [buf][b][tt][k] (k>=16 zero)
    __shared__ float Pre2[2][64];                      // dbuf layer-2 preacts [buf][b*4+g]
    __shared__ float Ybuf[16][16];                     // [b][tt] (wave-1 private)

    const int tid = threadIdx.x;
    const int wv  = tid >> 6;
    const int l   = tid & 63;
    const int q   = l & 15;
    const int hi  = l >> 4;
    const int b0  = blockIdx.x << 4;
    const int he  = (wv << 4) + q;
    const int sw  = (q & 7) << 4;

    ((u16x8*)A_h)[tid] = (u16x8){0,0,0,0,0,0,0,0};     // zero both A_h bufs (h_{-1}=0)

    // ---- B fragments, pre-scaled so MFMA acc is directly the exp2 argument ----
    bf16x8 Bf[4][3];
    #pragma unroll
    for (int g = 0; g < 4; ++g) {
        const float sc = (g == 2) ? TL2E : NL2E;
        const int n = (g << 6) + (wv << 4) + q;
        #pragma unroll
        for (int ks = 0; ks < 3; ++ks) {
            bf16x8 tmp;
            #pragma unroll
            for (int j = 0; j < 8; ++j) {
                const int k = ks * 32 + hi * 8 + j;
                float v = 0.f;
                if (k < 64)      v = w_hh1[n * 64 + k];
                else if (k < 80) v = w_ih1[n * 16 + (k - 64)];
                tmp[j] = (__bf16)(sc * v);
            }
            Bf[g][ks] = tmp;
        }
    }
    bf16x8 B2[2];                                      // layer-2 input proj (wave 3)
    {
        const float sc2 = (q == 2) ? TL2E : NL2E;
        #pragma unroll
        for (int ks = 0; ks < 2; ++ks) {
            bf16x8 tmp;
            #pragma unroll
            for (int j = 0; j < 8; ++j) {
                const int k = ks * 32 + hi * 8 + j;
                const float v = (q < 4) ? w_ih2[q * 64 + k] : 0.f;
                tmp[j] = (__bf16)(sc2 * v);
            }
            B2[ks] = tmp;
        }
    }

    // layer-1 biases as scaled acc-init values
    float accb[4];
    #pragma unroll
    for (int g = 0; g < 4; ++g) {
        const float sc = (g == 2) ? TL2E : NL2E;
        accb[g] = sc * (b_ih1[(g << 6) + he] + b_hh1[(g << 6) + he]);
    }

    // layer-2 constants (scaled)
    const float w2si = NL2E * w_hh2[0], w2sf = NL2E * w_hh2[1];
    const float w2sg = TL2E * w_hh2[2], w2so = NL2E * w_hh2[3];
    const float nb2i = NL2E * (b_ih2[0] + b_hh2[0]);
    const float nb2f = NL2E * (b_ih2[1] + b_hh2[1]);
    const float tb2g = TL2E * (b_ih2[2] + b_hh2[2]);
    const float nb2o = NL2E * (b_ih2[3] + b_hh2[3]);
    const float fcw = fc_w[0], fcb = fc_b[0];

    // ---- x staging: thread (bx,part) owns x[b0+bx][t0+part][0..15] ----
    const int bx = tid >> 4, part = tid & 15;
    const int swx = (bx & 7) << 4;
    const unsigned xo0 = (unsigned)(bx * 1024 + (((part << 6) +  0) ^ swx));
    const unsigned xo1 = (unsigned)(bx * 1024 + (((part << 6) + 16) ^ swx));
    const unsigned xo2 = (unsigned)(bx * 1024 + (((part << 6) + 32) ^ swx));
    const unsigned xo3 = (unsigned)(bx * 1024 + (((part << 6) + 48) ^ swx));
    const float* xrow = x + (size_t)(b0 + bx) * 4096 + part * 16;

    f32x4 xq0, xq1, xq2, xq3;
    auto stage_x = [&](int bufoff) {
        bf16x8 lo, hw;
        #pragma unroll
        for (int j = 0; j < 4; ++j) {
            lo[j] = (__bf16)xq0[j]; lo[4 + j] = (__bf16)xq1[j];
            hw[j] = (__bf16)xq2[j]; hw[4 + j] = (__bf16)xq3[j];
        }
        const u16x8 z = {0,0,0,0,0,0,0,0};
        char* base = (char*)Xc + bufoff;
        *(u16x8*)(base + xo0) = __builtin_bit_cast(u16x8, lo);
        *(u16x8*)(base + xo1) = __builtin_bit_cast(u16x8, hw);
        *(u16x8*)(base + xo2) = z;
        *(u16x8*)(base + xo3) = z;
    };

    // prologue: stage chunk 0 into buf 0, prefetch chunk 1 into regs
    xq0 = ((const f32x4*)xrow)[0]; xq1 = ((const f32x4*)xrow)[1];
    xq2 = ((const f32x4*)xrow)[2]; xq3 = ((const f32x4*)xrow)[3];
    stage_x(0);
    {
        const float* p = xrow + 256;
        xq0 = ((const f32x4*)p)[0]; xq1 = ((const f32x4*)p)[1];
        xq2 = ((const f32x4*)p)[2]; xq3 = ((const f32x4*)p)[3];
    }

    // invariant addresses
    const unsigned ar0 = (unsigned)((q * 128 +      hi * 16) ^ sw);
    const unsigned ar1 = (unsigned)((q * 128 + 64 + hi * 16) ^ sw);
    unsigned awb[4];
    #pragma unroll
    for (int j = 0; j < 4; ++j) {
        const int b = (hi << 2) + j;
        awb[j] = (unsigned)(b * 128 + ((he * 2) ^ ((b & 7) << 4)));
    }

    float c1[4] = {0.f, 0.f, 0.f, 0.f};   // plain array: ref-bindable, const-indexed
    float h2 = 0.f, c2 = 0.f;

    __syncthreads();   // prologue sync (full drain once is fine)

    #pragma unroll 2
    for (int t = 0; t < 256; ++t) {
        const int tt = t & 15;
        if (tt == 0 && t + 16 < 256) {
            stage_x(((((t >> 4) + 1) & 1)) << 14);     // next chunk -> idle buf
            if (t + 32 < 256) {
                const float* p = xrow + (t + 32) * 16;
                xq0 = ((const f32x4*)p)[0]; xq1 = ((const f32x4*)p)[1];
                xq2 = ((const f32x4*)p)[2]; xq3 = ((const f32x4*)p)[3];
            }
        }

        // A-frag reads: h_{t-1} from buf (t-1)&1, x from current chunk buf
        const int rb = ((t + 1) & 1) << 11;
        const u16x8 ra0 = *(const u16x8*)((const char*)A_h + rb + ar0);
        const u16x8 ra1 = *(const u16x8*)((const char*)A_h + rb + ar1);
        const u16x8 ra2 = *(const u16x8*)((const char*)Xc + (((t >> 4) & 1) << 14)
                                          + ((q * 1024 + (tt << 6) + (hi << 4)) ^ sw));

        // layer-2 + FC at lag 2 (wave 1, lanes 0..15 = batches)
        if (wv == 1 && t >= 2) {
            const int s = t - 2;
            if (l < 16) {
                const f32x4 p2 = *(const f32x4*)&Pre2[(t + 1) & 1][l << 2];
                const float zi = p2[0] + __builtin_fmaf(w2si, h2, nb2i);
                const float zf = p2[1] + __builtin_fmaf(w2sf, h2, nb2f);
                const float zg = p2[2] + __builtin_fmaf(w2sg, h2, tb2g);
                const float zo = p2[3] + __builtin_fmaf(w2so, h2, nb2o);
                h2 = cell_update(zi, zf, zg, zo, c2);
                Ybuf[l][s & 15] = __builtin_fmaf(fcw, h2, fcb);
            }
            if ((s & 15) == 15) {    // all 64 lanes flush 16 rows x 64B, coalesced
                float* op = out + (size_t)(b0 + (l >> 2)) * 256 + (s - 15) + ((l & 3) << 2);
                *(f32x4*)op = *(const f32x4*)&Ybuf[l >> 2][(l & 3) << 2];
            }
        }

        const bf16x8 a0 = __builtin_bit_cast(bf16x8, ra0);
        const bf16x8 a1 = __builtin_bit_cast(bf16x8, ra1);
        const bf16x8 a2 = __builtin_bit_cast(bf16x8, ra2);

        f32x4 g0 = {accb[0], accb[0], accb[0], accb[0]};
        f32x4 g1 = {accb[1], accb[1], accb[1], accb[1]};
        f32x4 g2 = {accb[2], accb[2], accb[2], accb[2]};
        f32x4 g3 = {accb[3], accb[3], accb[3], accb[3]};
        g0 = __builtin_amdgcn_mfma_f32_16x16x32_bf16(a0, Bf[0][0], g0, 0, 0, 0);
        g1 = __builtin_amdgcn_mfma_f32_16x16x32_bf16(a0, Bf[1][0], g1, 0, 0, 0);
        g2 = __builtin_amdgcn_mfma_f32_16x16x32_bf16(a0, Bf[2][0], g2, 0, 0, 0);
        g3 = __builtin_amdgcn_mfma_f32_16x16x32_bf16(a0, Bf[3][0], g3, 0, 0, 0);
        g0 = __builtin_amdgcn_mfma_f32_16x16x32_bf16(a1, Bf[0][1], g0, 0, 0, 0);
        g1 = __builtin_amdgcn_mfma_f32_16x16x32_bf16(a1, Bf[1][1], g1, 0, 0, 0);
        g2 = __builtin_amdgcn_mfma_f32_16x16x32_bf16(a1, Bf[2][1], g2, 0, 0, 0);
        g3 = __builtin_amdgcn_mfma_f32_16x16x32_bf16(a1, Bf[3][1], g3, 0, 0, 0);
        g0 = __builtin_amdgcn_mfma_f32_16x16x32_bf16(a2, Bf[0][2], g0, 0, 0, 0);
        g1 = __builtin_amdgcn_mfma_f32_16x16x32_bf16(a2, Bf[1][2], g1, 0, 0, 0);
        g2 = __builtin_amdgcn_mfma_f32_16x16x32_bf16(a2, Bf[2][2], g2, 0, 0, 0);
        g3 = __builtin_amdgcn_mfma_f32_16x16x32_bf16(a2, Bf[3][2], g3, 0, 0, 0);

        if (wv == 3) {   // layer-2 input projection of h_{t-1} -> Pre2[t&1]
            f32x4 p4 = {0.f, 0.f, 0.f, 0.f};
            p4 = __builtin_amdgcn_mfma_f32_16x16x32_bf16(a0, B2[0], p4, 0, 0, 0);
            p4 = __builtin_amdgcn_mfma_f32_16x16x32_bf16(a1, B2[1], p4, 0, 0, 0);
            if (q < 4) {
                #pragma unroll
                for (int r = 0; r < 4; ++r) Pre2[t & 1][((hi << 2) + r) * 4 + q] = p4[r];
            }
        }

        // elementwise: accs ARE the scaled preacts; write h_t to buf t&1
        char* AW = (char*)A_h + ((t & 1) << 11);
        #pragma unroll
        for (int j = 0; j < 4; ++j) {
            const float hv = cell_update(g0[j], g1[j], g2[j], g3[j], c1[j]);
            *(unsigned short*)(AW + awb[j]) = __builtin_bit_cast(unsigned short, (__bf16)hv);
        }

        // RAW barrier: only drain LDS ops (no vmcnt drain -> global ops float)
        asm volatile("s_waitcnt lgkmcnt(0)\n\ts_barrier" ::: "memory");
    }

    // ---- epilogue: layer-2 steps s=254 (Pre2[1]) and s=255 (fresh proj h_255) ----
    if (wv == 3) {
        const u16x8 ra0 = *(const u16x8*)((const char*)A_h + 2048 + ar0);
        const u16x8 ra1 = *(const u16x8*)((const char*)A_h + 2048 + ar1);
        f32x4 p4 = {0.f, 0.f, 0.f, 0.f};
        p4 = __builtin_amdgcn_mfma_f32_16x16x32_bf16(__builtin_bit_cast(bf16x8, ra0), B2[0], p4, 0, 0, 0);
        p4 = __builtin_amdgcn_mfma_f32_16x16x32_bf16(__builtin_bit_cast(bf16x8, ra1), B2[1], p4, 0, 0, 0);
        if (q < 4) {
            #pragma unroll
            for (int r = 0; r < 4; ++r) Pre2[0][((hi << 2) + r) * 4 + q] = p4[r];
        }
    }
    __syncthreads();
    if (wv == 1) {
        if (l < 16) {
            #pragma unroll
            for (int e = 0; e < 2; ++e) {   // e=0 -> s=254 (Pre2[1]), e=1 -> s=255 (Pre2[0])
                const f32x4 p2 = *(const f32x4*)&Pre2[1 - e][l << 2];
                const float zi = p2[0] + __builtin_fmaf(w2si, h2, nb2i);
                const float zf = p2[1] + __builtin_fmaf(w2sf, h2, nb2f);
                const float zg = p2[2] + __builtin_fmaf(w2sg, h2, tb2g);
                const float zo = p2[3] + __builtin_fmaf(w2so, h2, nb2o);
                h2 = cell_update(zi, zf, zg, zo, c2);
                Ybuf[l][14 + e] = __builtin_fmaf(fcw, h2, fcb);
            }
        }
        float* op = out + (size_t)(b0 + (l >> 2)) * 256 + 240 + ((l & 3) << 2);
        *(f32x4*)op = *(const f32x4*)&Ybuf[l >> 2][(l & 3) << 2];
    }
}

extern "C" void kernel_launch(void* const* d_in, const int* in_sizes, int n_in,
                              void* d_out, int out_size, void* d_ws, size_t ws_size,
                              hipStream_t stream) {
    (void)in_sizes; (void)n_in; (void)out_size; (void)d_ws; (void)ws_size;
    const float* x     = (const float*)d_in[0];
    const float* w_ih1 = (const float*)d_in[1];
    const float* w_hh1 = (const float*)d_in[2];
    const float* b_ih1 = (const float*)d_in[3];
    const float* b_hh1 = (const float*)d_in[4];
    const float* w_ih2 = (const float*)d_in[5];
    const float* w_hh2 = (const float*)d_in[6];
    const float* b_ih2 = (const float*)d_in[7];
    const float* b_hh2 = (const float*)d_in[8];
    const float* fc_w  = (const float*)d_in[9];
    const float* fc_b  = (const float*)d_in[10];
    lstm_fused<<<dim3(256), dim3(256), 0, stream>>>(
        x, w_ih1, w_hh1, b_ih1, b_hh1, w_ih2, w_hh2, b_ih2, b_hh2, fc_w, fc_b,
        (float*)d_out);
}